// Round 1
// baseline (908.448 us; speedup 1.0000x reference)
//
#include <hip/hip_runtime.h>

// RWKV-5 WKV recurrence, f32.
// B=4, T=4096, H=32, S=64. One wave per (b, h, d-group of 8).
// lane = s_group*8 + d_sub; each lane holds 8 state elems (column d, 8 s's).
// State kept in scaled form X = s_raw*SCALE:
//   X' = td*X + k*(v*SCALE);  wkv[d] = sum_s r[s]*(tf[s]*k[s]*vs[d] + X[s,d])
//   s_final = X/SCALE.

namespace {
constexpr int cB = 4;
constexpr int cT = 4096;
constexpr int cH = 32;
constexpr int cS = 64;
constexpr int cTS = cH * cS;      // 2048 floats per timestep
constexpr float cScale = 1.0f / 128.0f;
constexpr int cGroups = cT / 4;   // 1024 groups of 4 timesteps
}

__global__ __launch_bounds__(64)
void rwkv5_wkv_kernel(const float* __restrict__ K,
                      const float* __restrict__ V,
                      const float* __restrict__ R,
                      const float* __restrict__ S2in,
                      const float* __restrict__ TF,
                      const float* __restrict__ TD,
                      float* __restrict__ Out) {
    const int n    = blockIdx.x;
    const int dg   = n >> 7;      // d-group 0..7
    const int bh   = n & 127;     // 0..127 ; XCD = n%8 = bh%8 -> all dg of a bh co-located
    const int b    = bh >> 5;
    const int h    = bh & 31;
    const int lane = threadIdx.x;
    const int dsub = lane & 7;
    const int d    = dg * 8 + dsub;
    const int sb   = (lane >> 3) * 8;   // this lane's s-range start

    // per-lane constants (uniform across d_sub within an s-group)
    float tf[8], td[8];
#pragma unroll
    for (int j = 0; j < 8; ++j) {
        tf[j] = TF[h * cS + sb + j];
        td[j] = TD[h * cS + sb + j];
    }

    // initial state, scaled
    float s2[8];
#pragma unroll
    for (int j = 0; j < 8; ++j)
        s2[j] = S2in[((size_t)bh * cS + sb + j) * cS + d] * cScale;

    const float* kp = K + (size_t)b * cT * cTS + h * cS + sb;
    const float* rp = R + (size_t)b * cT * cTS + h * cS + sb;
    const float* vp = V + (size_t)b * cT * cTS + h * cS + d;
    float*       op = Out + (size_t)b * cT * cTS + h * cS + d;

    // double-buffered register prefetch, 4 timesteps per group
    float4 kA[4][2], rA[4][2], kBuf[4][2], rBuf[4][2];
    float  vA[4], vBuf[4];

    auto loadG = [&](int g, float4 (&kb)[4][2], float4 (&rb)[4][2],
                     float (&vb)[4]) {
        const int gg = (g < cGroups) ? g : (cGroups - 1);  // clamp tail prefetch
        const size_t off = (size_t)gg * 4 * cTS;
#pragma unroll
        for (int i = 0; i < 4; ++i) {
            const float* kk = kp + off + (size_t)i * cTS;
            const float* rr = rp + off + (size_t)i * cTS;
            kb[i][0] = *reinterpret_cast<const float4*>(kk);
            kb[i][1] = *reinterpret_cast<const float4*>(kk + 4);
            rb[i][0] = *reinterpret_cast<const float4*>(rr);
            rb[i][1] = *reinterpret_cast<const float4*>(rr + 4);
            vb[i]    = vp[off + (size_t)i * cTS];
        }
    };

    auto compG = [&](int g, float4 (&kb)[4][2], float4 (&rb)[4][2],
                     float (&vb)[4]) {
        float acc[4];
#pragma unroll
        for (int i = 0; i < 4; ++i) {
            const float vs = vb[i] * cScale;
            float kk[8] = {kb[i][0].x, kb[i][0].y, kb[i][0].z, kb[i][0].w,
                           kb[i][1].x, kb[i][1].y, kb[i][1].z, kb[i][1].w};
            float rr[8] = {rb[i][0].x, rb[i][0].y, rb[i][0].z, rb[i][0].w,
                           rb[i][1].x, rb[i][1].y, rb[i][1].z, rb[i][1].w};
            float a = 0.0f;
#pragma unroll
            for (int j = 0; j < 8; ++j) {
                const float kv = kk[j] * vs;
                a = fmaf(rr[j], fmaf(tf[j], kv, s2[j]), a);
                s2[j] = fmaf(td[j], s2[j], kv);
            }
            acc[i] = a;
        }
        // batched 3-level butterfly over the 8 s-groups (masks 8,16,32);
        // 4 independent reductions so shuffle latencies overlap
#pragma unroll
        for (int i = 0; i < 4; ++i) acc[i] += __shfl_xor(acc[i], 8, 64);
#pragma unroll
        for (int i = 0; i < 4; ++i) acc[i] += __shfl_xor(acc[i], 16, 64);
#pragma unroll
        for (int i = 0; i < 4; ++i) acc[i] += __shfl_xor(acc[i], 32, 64);
        if (sb == 0) {
#pragma unroll
            for (int i = 0; i < 4; ++i)
                op[(size_t)(g * 4 + i) * cTS] = acc[i];
        }
    };

    loadG(0, kA, rA, vA);
    for (int g = 0; g < cGroups; g += 2) {
        loadG(g + 1, kBuf, rBuf, vBuf);
        compG(g, kA, rA, vA);
        loadG(g + 2, kA, rA, vA);   // clamped at tail; compute never consumes OOB group
        compG(g + 1, kBuf, rBuf, vBuf);
    }

    // final state: s_final = X / SCALE
    float* o2 = Out + (size_t)cB * cT * cTS + (size_t)bh * cS * cS;
#pragma unroll
    for (int j = 0; j < 8; ++j)
        o2[(size_t)(sb + j) * cS + d] = s2[j] * 128.0f;
}

extern "C" void kernel_launch(void* const* d_in, const int* in_sizes, int n_in,
                              void* d_out, int out_size, void* d_ws,
                              size_t ws_size, hipStream_t stream) {
    const float* K    = (const float*)d_in[0];
    const float* V    = (const float*)d_in[1];
    const float* R    = (const float*)d_in[2];
    const float* S2in = (const float*)d_in[3];
    const float* TF   = (const float*)d_in[4];
    const float* TD   = (const float*)d_in[5];
    float* OutP = (float*)d_out;
    (void)in_sizes; (void)n_in; (void)d_ws; (void)ws_size; (void)out_size;
    rwkv5_wkv_kernel<<<dim3(cB * cH * 8), dim3(64), 0, stream>>>(
        K, V, R, S2in, TF, TD, OutP);
}